// Round 10
// baseline (179.111 us; speedup 1.0000x reference)
//
#include <hip/hip_runtime.h>

typedef unsigned long long ull;

#define NUM_K   512
#define DIM     64
#define N_ROWS  (32 * 64 * 64)     // 131072 rows
#define HW      4096               // 64*64
#define CHW     (64 * 4096)        // per-batch stride (C*H*W) = 2^18

// Output buffer float32, flat layout = reference return order:
//   [ discrete (131072) | quantized NCHW (8388608) | loss (1) ]
#define IDX_OFF  0
#define Q_OFF    N_ROWS
#define LOSS_OFF (N_ROWS + 32 * 64 * 4096)   // 8519680

#define CAP     8      // candidate list capacity per row
#define TILE_R  128    // rows per block (1024 blocks)
#define NBLK    (N_ROWS / TILE_R)

// Split-bf16 window (validated R2-R9): |t_hat - t_exact| <~ 6.5e-5*maxx*sumw
// one-sided; two-sided via 2*SWMAX. WK1S=1e-4 gives 1.5x margin; WK2S covers
// reorder rounding 5x.
#define WK1S    1.0e-4f
#define WK2S    2.0e-5f

// Workspace (dwords):
//   [0,32768)  A-frag table: 128 granules x 256 dwords
//   [32768,33280) w2all (exact ||w||^2)   [33280,33792) w2h (0.5*||w||^2)
//   [33792,33800) 8 swmax partials
//   bytes [147456,147456+8192): 1024 lslots (double)
#define WS_W2_OFF    32768
#define WS_W2H_OFF   33280
#define WS_SWMAX_OFF 33792
#define WS_LSL_BYTE  147456
#define WS_NEED      (147456 + NBLK * 8)   // 155648

typedef __attribute__((ext_vector_type(8)))  short bf16x8;   // 8 bf16 = 4 VGPRs
typedef __attribute__((ext_vector_type(16))) float f32x16;   // 32x32 acc

typedef unsigned uGLB __attribute__((address_space(1)));
typedef unsigned uLDS __attribute__((address_space(3)));
// async global->LDS, 16B/lane; LDS dest is wave-uniform base + lane*16
#define GLD16(g, l) __builtin_amdgcn_global_load_lds((const uGLB*)(g), (uLDS*)(l), 16, 0, 0)

// numpy pairwise_sum (n=64) of squares, contiguous (validated bit-exact)
#define NP_SUMSQ64(SRC, DST)                                                   \
    do {                                                                       \
        float r_[8];                                                           \
        _Pragma("unroll")                                                      \
        for (int j_ = 0; j_ < 8; ++j_) r_[j_] = __fmul_rn((SRC)[j_], (SRC)[j_]); \
        _Pragma("unroll")                                                      \
        for (int i_ = 8; i_ < 64; i_ += 8) {                                   \
            _Pragma("unroll")                                                  \
            for (int j_ = 0; j_ < 8; ++j_)                                     \
                r_[j_] = __fadd_rn(r_[j_], __fmul_rn((SRC)[i_ + j_], (SRC)[i_ + j_])); \
        }                                                                      \
        (DST) = __fadd_rn(__fadd_rn(__fadd_rn(r_[0], r_[1]), __fadd_rn(r_[2], r_[3])), \
                          __fadd_rn(__fadd_rn(r_[4], r_[5]), __fadd_rn(r_[6], r_[7]))); \
    } while (0)

// same pairwise order, strided source (element d at (XC)[d*HW])
#define NP_SUMSQ64_G(XC, DST)                                                  \
    do {                                                                       \
        float r_[8];                                                           \
        _Pragma("unroll")                                                      \
        for (int j_ = 0; j_ < 8; ++j_) {                                       \
            float v_ = (XC)[(size_t)j_ * HW];                                  \
            r_[j_] = __fmul_rn(v_, v_);                                        \
        }                                                                      \
        _Pragma("unroll")                                                      \
        for (int i_ = 8; i_ < 64; i_ += 8) {                                   \
            _Pragma("unroll")                                                  \
            for (int j_ = 0; j_ < 8; ++j_) {                                   \
                float v_ = (XC)[(size_t)(i_ + j_) * HW];                       \
                r_[j_] = __fadd_rn(r_[j_], __fmul_rn(v_, v_));                 \
            }                                                                  \
        }                                                                      \
        (DST) = __fadd_rn(__fadd_rn(__fadd_rn(r_[0], r_[1]), __fadd_rn(r_[2], r_[3])), \
                          __fadd_rn(__fadd_rn(r_[4], r_[5]), __fadd_rn(r_[6], r_[7]))); \
    } while (0)

__device__ __forceinline__ unsigned bf16rn(float f) {   // RN-to-nearest-even, finite
    unsigned u = __float_as_uint(f);
    return (u + 0x7fffu + ((u >> 16) & 1u)) >> 16;
}
__device__ __forceinline__ float bf2f(unsigned h) { return __uint_as_float(h << 16); }

// Exact reference-semantics distance (contiguous / strided x)
__device__ __forceinline__ float evald(const float* __restrict__ xr,
                                       const float* __restrict__ wc,
                                       float A, float w2c) {
    float m = 0.0f;
    #pragma unroll
    for (int d = 0; d < DIM; ++d) m = __fmaf_rn(xr[d], wc[d], m);
    return __fadd_rn(__fsub_rn(A, __fmul_rn(2.0f, m)), w2c);
}
__device__ __forceinline__ float evald_g(const float* __restrict__ xcol,
                                         const float* __restrict__ wc,
                                         float A, float w2c) {
    float m = 0.0f;
    #pragma unroll
    for (int d = 0; d < DIM; ++d) m = __fmaf_rn(xcol[(size_t)d * HW], wc[d], m);
    return __fadd_rn(__fsub_rn(A, __fmul_rn(2.0f, m)), w2c);
}

// ---- prep (8 blocks x 64): A-frag table (32-code tiles, 32x32x16 layout) ----
// Granule g = T*8 + s*2 + hl: 256 dwords; lane-slot l = m + 32*kh at l*4;
// code c = 32T+m, k = 16s + 8kh + e. (validated R8/R9, absmax 0.0)
__global__ __launch_bounds__(64) void vq_prep8(const float* __restrict__ weight,
                                               unsigned* __restrict__ ws) {
    const int c = blockIdx.x * 64 + threadIdx.x;    // 512 codes
    const int T = c >> 5, m = c & 31;
    const float* wr = weight + c * DIM;
    float wv[DIM];
    #pragma unroll
    for (int d = 0; d < DIM; d += 4) {
        float4 t4 = *(const float4*)&wr[d];
        wv[d] = t4.x; wv[d + 1] = t4.y; wv[d + 2] = t4.z; wv[d + 3] = t4.w;
    }
    float s; NP_SUMSQ64(wv, s);
    ((float*)(ws + WS_W2_OFF))[c]  = s;             // exact pairwise ||w||^2
    ((float*)(ws + WS_W2H_OFF))[c] = 0.5f * s;      // exact (0.5*fp32)
    float sa = 0.0f;
    #pragma unroll
    for (int d = 0; d < DIM; ++d) sa = __fadd_rn(sa, fabsf(wv[d]));
    float sv = sa * 1.0002f + 1e-7f;                // sum|w| + slack

    #pragma unroll
    for (int s4 = 0; s4 < 4; ++s4) {
        const int gH = T * 8 + s4 * 2, gL = gH + 1;
        #pragma unroll
        for (int kh = 0; kh < 2; ++kh) {            // lane-half: k = 16s4+8kh+e
            unsigned hu[4], lu[4];
            #pragma unroll
            for (int p = 0; p < 4; ++p) {
                float e0 = wv[16 * s4 + 8 * kh + 2 * p];
                float e1 = wv[16 * s4 + 8 * kh + 2 * p + 1];
                unsigned h0 = bf16rn(e0), h1 = bf16rn(e1);
                float r0 = __fsub_rn(e0, bf2f(h0));   // exact residual
                float r1 = __fsub_rn(e1, bf2f(h1));
                hu[p] = h0 | (h1 << 16);
                lu[p] = bf16rn(r0) | (bf16rn(r1) << 16);
            }
            const int slot = (m + 32 * kh) * 4;
            *(uint4*)&ws[gH * 256 + slot] = make_uint4(hu[0], hu[1], hu[2], hu[3]);
            *(uint4*)&ws[gL * 256 + slot] = make_uint4(lu[0], lu[1], lu[2], lu[3]);
        }
    }
    #pragma unroll
    for (int mk = 1; mk <= 32; mk <<= 1) sv = fmaxf(sv, __shfl_xor(sv, mk));
    if (threadIdx.x == 0) ((float*)(ws + WS_SWMAX_OFF))[blockIdx.x] = sv;
}

// ---- main: R8 structure + LDS w2h (off critical path) + epilogue x-reuse ----
__global__ __launch_bounds__(256, 3) void vq_mfma10(const float* __restrict__ x_in,
                                                    const float* __restrict__ weight,
                                                    const unsigned* __restrict__ frg,
                                                    double* __restrict__ lslots,
                                                    float* __restrict__ out) {
    __shared__ __align__(16) unsigned dbuf[2][4096];   // 32 KB frag double-buffer
    __shared__ __align__(16) float w2h_l[NUM_K];       // 0.5*||w||^2 (acc init)
    __shared__ __align__(16) float w2a_l[NUM_K];       // exact ||w||^2 (rescue)
    __shared__ int   cntL[TILE_R];
    __shared__ unsigned short listL[TILE_R * CAP];
    __shared__ int   ilds[TILE_R];
    __shared__ float wsum[4];
    // ~39.9 KB -> 4 blocks/CU

    const int tid   = threadIdx.x;
    const int lane  = tid & 63;
    const int wid   = tid >> 6;        // 4 waves; wave owns rows [wbase, wbase+32)
    const int wbase = wid * 32;
    const int n31   = lane & 31;       // this lane's row (B col) within wave
    const int kh    = lane >> 5;       // lane half: k sub-range / code group +4kh

    const int rowbase = blockIdx.x * TILE_R;
    const int b       = rowbase >> 12;
    const int hw0     = rowbase & 4095;
    const float* xb   = x_in + (size_t)b * CHW + hw0;

    // ---- issue stage of chunk 0 (granules 0..15) ----
    #pragma unroll
    for (int i = 0; i < 4; ++i) {
        int sg = wid * 4 + i;
        GLD16(frg + sg * 256 + lane * 4, &dbuf[0][sg * 256]);
    }
    // ---- stage w2h/w2a tables into LDS (1 GLD16 per wave) ----
    if (wid == 0)      GLD16(frg + WS_W2H_OFF       + lane * 4, (unsigned*)&w2h_l[0]);
    else if (wid == 1) GLD16(frg + WS_W2H_OFF + 256 + lane * 4, (unsigned*)&w2h_l[256]);
    else if (wid == 2) GLD16(frg + WS_W2_OFF        + lane * 4, (unsigned*)&w2a_l[0]);
    else               GLD16(frg + WS_W2_OFF  + 256 + lane * 4, (unsigned*)&w2a_l[256]);

    // ---- B fragments: NEGATED x row, hi + exact-residual lo; keep x in regs ----
    bf16x8 bh[4], bl[4];
    float xreg[32];                    // this lane's 32 x elems (k=16s+8kh+e)
    float mx = 0.0f;
    const float* xp = xb + wbase + n31;
    #pragma unroll
    for (int s = 0; s < 4; ++s) {
        union { unsigned u[4]; bf16x8 v; } ch, cl;
        #pragma unroll
        for (int p = 0; p < 4; ++p) {
            const int k0 = 16 * s + 8 * kh + 2 * p;
            float x0 = xp[(size_t)k0 * HW];
            float x1 = xp[(size_t)(k0 + 1) * HW];
            xreg[8 * s + 2 * p]     = x0;
            xreg[8 * s + 2 * p + 1] = x1;
            mx = fmaxf(mx, fmaxf(fabsf(x0), fabsf(x1)));
            float e0 = -x0, e1 = -x1;              // negate: acc = w2h - x.w
            unsigned h0 = bf16rn(e0), h1 = bf16rn(e1);
            float r0 = __fsub_rn(e0, bf2f(h0));    // exact residual
            float r1 = __fsub_rn(e1, bf2f(h1));
            ch.u[p] = h0 | (h1 << 16);
            cl.u[p] = bf16rn(r0) | (bf16rn(r1) << 16);
        }
        bh[s] = ch.v;
        bl[s] = cl.v;
    }
    mx = fmaxf(mx, __shfl_xor(mx, 32));            // full row max (pair lanes)
    if (tid < TILE_R) cntL[tid] = 0;

    const float* swp = (const float*)(frg + WS_SWMAX_OFF);
    float SWMAX = swp[0];
    #pragma unroll
    for (int i = 1; i < 8; ++i) SWMAX = fmaxf(SWMAX, swp[i]);
    const float gthr = __fmaf_rn(WK1S * mx, 2.0f * SWMAX, WK2S);
    float thr = 3.4e38f;
    __syncthreads();   // drains stage-0 + w2h/w2a vmcnt; cntL visible

    // ---- K-loop: 8 chunks x 2 tiles (64 codes); stage next while computing ----
    for (int c = 0; c < 8; ++c) {
        const int par = c & 1;
        if (c < 7) {
            const int nxt = par ^ 1;
            #pragma unroll
            for (int i = 0; i < 4; ++i) {
                int sg = wid * 4 + i;
                GLD16(frg + (c + 1) * 4096 + sg * 256 + lane * 4,
                      &dbuf[nxt][sg * 256]);
            }
        }

        // acc init = 0.5*||w||^2 from LDS broadcast (fast, off HBM/L2 path)
        // reg r -> code (r&3)+8*(r>>2)+4*kh : float4 groups at +0,8,16,24
        f32x16 acc0, acc1;
        {
            const float* wa = &w2h_l[(2 * c) * 32 + 4 * kh];
            float4 a0 = *(const float4*)&wa[0];
            float4 a1 = *(const float4*)&wa[8];
            float4 a2 = *(const float4*)&wa[16];
            float4 a3 = *(const float4*)&wa[24];
            acc0[0]=a0.x; acc0[1]=a0.y; acc0[2]=a0.z; acc0[3]=a0.w;
            acc0[4]=a1.x; acc0[5]=a1.y; acc0[6]=a1.z; acc0[7]=a1.w;
            acc0[8]=a2.x; acc0[9]=a2.y; acc0[10]=a2.z; acc0[11]=a2.w;
            acc0[12]=a3.x; acc0[13]=a3.y; acc0[14]=a3.z; acc0[15]=a3.w;
            const float* wb = &w2h_l[(2 * c + 1) * 32 + 4 * kh];
            float4 c0 = *(const float4*)&wb[0];
            float4 c1 = *(const float4*)&wb[8];
            float4 c2 = *(const float4*)&wb[16];
            float4 c3 = *(const float4*)&wb[24];
            acc1[0]=c0.x; acc1[1]=c0.y; acc1[2]=c0.z; acc1[3]=c0.w;
            acc1[4]=c1.x; acc1[5]=c1.y; acc1[6]=c1.z; acc1[7]=c1.w;
            acc1[8]=c2.x; acc1[9]=c2.y; acc1[10]=c2.z; acc1[11]=c2.w;
            acc1[12]=c3.x; acc1[13]=c3.y; acc1[14]=c3.z; acc1[15]=c3.w;
        }

        #pragma unroll
        for (int s = 0; s < 4; ++s) {
            bf16x8 ah0 = *(const bf16x8*)&dbuf[par][(s * 2 + 0) * 256 + lane * 4];
            bf16x8 al0 = *(const bf16x8*)&dbuf[par][(s * 2 + 1) * 256 + lane * 4];
            bf16x8 ah1 = *(const bf16x8*)&dbuf[par][(8 + s * 2 + 0) * 256 + lane * 4];
            bf16x8 al1 = *(const bf16x8*)&dbuf[par][(8 + s * 2 + 1) * 256 + lane * 4];
            acc0 = __builtin_amdgcn_mfma_f32_32x32x16_bf16(ah0, bh[s], acc0, 0, 0, 0);
            acc1 = __builtin_amdgcn_mfma_f32_32x32x16_bf16(ah1, bh[s], acc1, 0, 0, 0);
            acc0 = __builtin_amdgcn_mfma_f32_32x32x16_bf16(al0, bh[s], acc0, 0, 0, 0);
            acc1 = __builtin_amdgcn_mfma_f32_32x32x16_bf16(al1, bh[s], acc1, 0, 0, 0);
            acc0 = __builtin_amdgcn_mfma_f32_32x32x16_bf16(ah0, bl[s], acc0, 0, 0, 0);
            acc1 = __builtin_amdgcn_mfma_f32_32x32x16_bf16(ah1, bl[s], acc1, 0, 0, 0);
        }

        // ---- per-tile: in-lane min16 + ONE pair-shfl; window; collect ----
        #pragma unroll
        for (int tl = 0; tl < 2; ++tl) {
            float tmin = 3.4e38f;
            #pragma unroll
            for (int r = 0; r < 16; ++r)
                tmin = fminf(tmin, (tl ? acc1[r] : acc0[r]));
            float tlr = fminf(tmin, __shfl_xor(tmin, 32));
            thr = fminf(thr, __fadd_rn(tlr, gthr));
            if (tmin <= thr) {
                const int cb = (2 * c + tl) * 32 + 4 * kh;
                const int rr = wbase + n31;
                #pragma unroll
                for (int r = 0; r < 16; ++r) {
                    float tv = (tl ? acc1[r] : acc0[r]);
                    if (tv <= thr) {
                        int code = cb + (r & 3) + 8 * (r >> 2);
                        int cn = atomicAdd(&cntL[rr], 1);
                        if (cn < CAP) listL[rr * CAP + cn] = (unsigned short)code;
                    }
                }
            }
        }

        __syncthreads();   // dbuf[nxt] staged + all reads of dbuf[par] done
    }

    // ---- rescue: cnt==1 -> decided; else exact fp32 chain, smallest-idx ties ----
    if (lane < 32) {
        const int r   = wbase + lane;
        const int cnt = cntL[r];
        if (cnt == 1) {
            int bi = listL[r * CAP];
            ilds[r] = bi;
            out[IDX_OFF + rowbase + r] = (float)bi;
        } else if (cnt >= 2 && cnt <= CAP) {
            const float* xcol = xb + r;
            float A; NP_SUMSQ64_G(xcol, A);
            float bd = 3.4e38f; int bi = 1 << 30;
            for (int t2 = 0; t2 < cnt; ++t2) {
                int cd = listL[r * CAP + t2];
                float d2 = evald_g(xcol, weight + cd * DIM, A, w2a_l[cd]);
                if (d2 < bd || (d2 == bd && cd < bi)) { bd = d2; bi = cd; }
            }
            ilds[r] = bi;
            out[IDX_OFF + rowbase + r] = (float)bi;
        }
    }
    // cooperative exact full scan for overflow rows (rare; correctness backstop)
    for (int rr = 0; rr < 32; ++rr) {
        int r   = wbase + rr;
        int cnt = cntL[r];
        if (cnt < 1 || cnt > CAP) {
            const float* xcol = xb + r;
            float A; NP_SUMSQ64_G(xcol, A);
            float bd = 3.4e38f; int bi = 1 << 30;
            #pragma unroll
            for (int t2 = 0; t2 < 8; ++t2) {
                int cd = t2 * 64 + lane;
                float d2 = evald_g(xcol, weight + cd * DIM, A, w2a_l[cd]);
                if (d2 < bd || (d2 == bd && cd < bi)) { bd = d2; bi = cd; }
            }
            ull key = ((ull)__float_as_uint(bd) << 32) | (unsigned)bi;
            #pragma unroll
            for (int mk = 1; mk <= 32; mk <<= 1) {
                ull o = __shfl_xor(key, mk);
                if (o < key) key = o;
            }
            if (lane == 0) {
                int bi2 = (int)(key & 0xffffffffu);
                ilds[r] = bi2;
                out[IDX_OFF + rowbase + r] = (float)bi2;
            }
        }
    }
    __syncthreads();   // ilds visible

    // ---- quantize epilogue + loss: x from xreg (no re-read); per-elem exact ----
    {
        const int row = wbase + n31;
        const int bi  = ilds[row];
        const float* wrow = weight + bi * DIM;
        float* ob = out + Q_OFF + (size_t)b * CHW + hw0 + row;
        float lsum = 0.0f;
        #pragma unroll
        for (int s = 0; s < 4; ++s) {
            #pragma unroll
            for (int e = 0; e < 8; ++e) {
                const int k = 16 * s + 8 * kh + e;
                float xd   = xreg[8 * s + e];
                float wq   = wrow[k];
                float diff = __fsub_rn(wq, xd);
                ob[(size_t)k * HW] = __fadd_rn(xd, diff);
                lsum = fmaf(diff, diff, lsum);
            }
        }
        #pragma unroll
        for (int off = 32; off > 0; off >>= 1) lsum += __shfl_down(lsum, off);
        if (lane == 0) wsum[wid] = lsum;
    }
    __syncthreads();
    if (tid == 0) {
        double s = 0.0;
        #pragma unroll
        for (int i = 0; i < 4; ++i) s += (double)wsum[i];
        lslots[blockIdx.x] = s;
    }
}

__global__ void vq_finalizeN(const double* __restrict__ lslots, int n,
                             float* __restrict__ out) {
    double s = 0.0;
    for (int i = threadIdx.x; i < n; i += 64) s += lslots[i];
    #pragma unroll
    for (int off = 32; off > 0; off >>= 1) s += __shfl_down(s, off);
    if (threadIdx.x == 0) {
        double m = s / 8388608.0;
        out[LOSS_OFF] = (float)(m + 0.25 * m);   // q_latent + 0.25 * e_latent
    }
}

// ---------------- scalar fallback (validated), used only if ws tiny ----------
__global__ void vq_zero(double* __restrict__ loss_acc) {
    if (threadIdx.x == 0) *loss_acc = 0.0;
}

__global__ __launch_bounds__(256) void vq_fused(const float* __restrict__ x_in,
                                                const float* __restrict__ weight,
                                                double* __restrict__ loss_acc,
                                                float* __restrict__ out) {
    __shared__ float w2s[NUM_K];
    for (int k = threadIdx.x; k < NUM_K; k += 256) {
        const float* wk = weight + k * DIM;
        float s; NP_SUMSQ64(wk, s);
        w2s[k] = s;
    }
    __syncthreads();

    const int n  = blockIdx.x * 256 + threadIdx.x;
    const int b  = n >> 12;
    const int hw = n & 4095;
    const float* xp = x_in + b * CHW + hw;
    float x[DIM];
    #pragma unroll
    for (int d = 0; d < DIM; ++d) x[d] = xp[d * HW];

    float A; NP_SUMSQ64(x, A);

    float best = 3.4e38f;
    int   bi   = 0;
    for (int k = 0; k < NUM_K; k += 4) {
        const float* w0 = weight + k * DIM;
        float m0 = 0.f, m1 = 0.f, m2 = 0.f, m3 = 0.f;
        #pragma unroll
        for (int d = 0; d < DIM; ++d) {
            float xd = x[d];
            m0 = __fmaf_rn(xd, w0[d],           m0);
            m1 = __fmaf_rn(xd, w0[DIM + d],     m1);
            m2 = __fmaf_rn(xd, w0[2 * DIM + d], m2);
            m3 = __fmaf_rn(xd, w0[3 * DIM + d], m3);
        }
        float d0 = __fadd_rn(__fsub_rn(A, __fmul_rn(2.0f, m0)), w2s[k]);
        float d1 = __fadd_rn(__fsub_rn(A, __fmul_rn(2.0f, m1)), w2s[k + 1]);
        float d2 = __fadd_rn(__fsub_rn(A, __fmul_rn(2.0f, m2)), w2s[k + 2]);
        float d3 = __fadd_rn(__fsub_rn(A, __fmul_rn(2.0f, m3)), w2s[k + 3]);
        if (d0 < best) { best = d0; bi = k; }
        if (d1 < best) { best = d1; bi = k + 1; }
        if (d2 < best) { best = d2; bi = k + 2; }
        if (d3 < best) { best = d3; bi = k + 3; }
    }
    const int idx = bi;

    out[IDX_OFF + n] = (float)idx;
    const float* qrow = weight + idx * DIM;
    float* oq = out + Q_OFF + b * CHW + hw;
    float lsum = 0.0f;
    #pragma unroll
    for (int d = 0; d < DIM; ++d) {
        float xd   = xp[d * HW];
        float diff = __fsub_rn(qrow[d], xd);
        oq[d * HW] = __fadd_rn(xd, diff);
        lsum = fmaf(diff, diff, lsum);
    }
    #pragma unroll
    for (int off = 32; off > 0; off >>= 1) lsum += __shfl_down(lsum, off);
    __shared__ float wsum[4];
    if ((threadIdx.x & 63) == 0) wsum[threadIdx.x >> 6] = lsum;
    __syncthreads();
    if (threadIdx.x == 0)
        atomicAdd(loss_acc, (double)((wsum[0] + wsum[1]) + (wsum[2] + wsum[3])));
}

__global__ void vq_finalize(const double* __restrict__ loss_acc,
                            float* __restrict__ out) {
    double m = *loss_acc / 8388608.0;
    out[LOSS_OFF] = (float)(m + 0.25 * m);
}

extern "C" void kernel_launch(void* const* d_in, const int* in_sizes, int n_in,
                              void* d_out, int out_size, void* d_ws, size_t ws_size,
                              hipStream_t stream) {
    const float* x = (const float*)d_in[0];    // inputs  [32,64,64,64] NCHW fp32
    const float* w = (const float*)d_in[1];    // weight  [512,64] fp32
    float* out = (float*)d_out;

    if (ws_size >= WS_NEED) {
        unsigned* ws32 = (unsigned*)d_ws;
        double* lslots = (double*)((char*)d_ws + WS_LSL_BYTE);
        vq_prep8<<<8, 64, 0, stream>>>(w, ws32);
        vq_mfma10<<<NBLK, 256, 0, stream>>>(x, w, ws32, lslots, out);
        vq_finalizeN<<<1, 64, 0, stream>>>(lslots, NBLK, out);
    } else {
        double* loss_acc = (double*)d_ws;
        vq_zero<<<1, 64, 0, stream>>>(loss_acc);
        vq_fused<<<512, 256, 0, stream>>>(x, w, loss_acc, out);
        vq_finalize<<<1, 1, 0, stream>>>(loss_acc, out);
    }
}

// Round 11
// 166.968 us; speedup vs baseline: 1.0727x; 1.0727x over previous
//
#include <hip/hip_runtime.h>

typedef unsigned long long ull;

#define NUM_K   512
#define DIM     64
#define N_ROWS  (32 * 64 * 64)     // 131072 rows
#define HW      4096               // 64*64
#define CHW     (64 * 4096)        // per-batch stride (C*H*W) = 2^18

// Output buffer float32, flat layout = reference return order:
//   [ discrete (131072) | quantized NCHW (8388608) | loss (1) ]
#define IDX_OFF  0
#define Q_OFF    N_ROWS
#define LOSS_OFF (N_ROWS + 32 * 64 * 4096)   // 8519680

#define CAP     8      // candidate list capacity per row
#define TILE_R  128    // rows per block (1024 blocks)
#define NBLK    (N_ROWS / TILE_R)

// Split-bf16 window (validated R2-R10): |t_hat - t_exact| <~ 6.5e-5*maxx*sumw
// one-sided; two-sided via 2*SWMAX. WK1S=1e-4 gives 1.5x margin; WK2S covers
// reorder rounding 5x.
#define WK1S    1.0e-4f
#define WK2S    2.0e-5f

// Workspace (dwords):
//   [0,32768)  A-frag table: 128 granules x 256 dwords
//   [32768,33280) w2all (exact ||w||^2)   [33280,33792) w2h (0.5*||w||^2)
//   [33792,33800) 8 swmax partials
//   bytes [147456,147464): lossacc (double)   [147464,147468): arrival cnt
#define WS_W2_OFF    32768
#define WS_W2H_OFF   33280
#define WS_SWMAX_OFF 33792
#define WS_LSL_BYTE  147456
#define WS_NEED      (147456 + 16)

typedef __attribute__((ext_vector_type(8)))  short bf16x8;   // 8 bf16 = 4 VGPRs
typedef __attribute__((ext_vector_type(16))) float f32x16;   // 32x32 acc

typedef unsigned uGLB __attribute__((address_space(1)));
typedef unsigned uLDS __attribute__((address_space(3)));
// async global->LDS, 16B/lane; LDS dest is wave-uniform base + lane*16
#define GLD16(g, l) __builtin_amdgcn_global_load_lds((const uGLB*)(g), (uLDS*)(l), 16, 0, 0)

// numpy pairwise_sum (n=64) of squares, contiguous (validated bit-exact)
#define NP_SUMSQ64(SRC, DST)                                                   \
    do {                                                                       \
        float r_[8];                                                           \
        _Pragma("unroll")                                                      \
        for (int j_ = 0; j_ < 8; ++j_) r_[j_] = __fmul_rn((SRC)[j_], (SRC)[j_]); \
        _Pragma("unroll")                                                      \
        for (int i_ = 8; i_ < 64; i_ += 8) {                                   \
            _Pragma("unroll")                                                  \
            for (int j_ = 0; j_ < 8; ++j_)                                     \
                r_[j_] = __fadd_rn(r_[j_], __fmul_rn((SRC)[i_ + j_], (SRC)[i_ + j_])); \
        }                                                                      \
        (DST) = __fadd_rn(__fadd_rn(__fadd_rn(r_[0], r_[1]), __fadd_rn(r_[2], r_[3])), \
                          __fadd_rn(__fadd_rn(r_[4], r_[5]), __fadd_rn(r_[6], r_[7]))); \
    } while (0)

// same pairwise order, strided source (element d at (XC)[d*HW])
#define NP_SUMSQ64_G(XC, DST)                                                  \
    do {                                                                       \
        float r_[8];                                                           \
        _Pragma("unroll")                                                      \
        for (int j_ = 0; j_ < 8; ++j_) {                                       \
            float v_ = (XC)[(size_t)j_ * HW];                                  \
            r_[j_] = __fmul_rn(v_, v_);                                        \
        }                                                                      \
        _Pragma("unroll")                                                      \
        for (int i_ = 8; i_ < 64; i_ += 8) {                                   \
            _Pragma("unroll")                                                  \
            for (int j_ = 0; j_ < 8; ++j_) {                                   \
                float v_ = (XC)[(size_t)(i_ + j_) * HW];                       \
                r_[j_] = __fadd_rn(r_[j_], __fmul_rn(v_, v_));                 \
            }                                                                  \
        }                                                                      \
        (DST) = __fadd_rn(__fadd_rn(__fadd_rn(r_[0], r_[1]), __fadd_rn(r_[2], r_[3])), \
                          __fadd_rn(__fadd_rn(r_[4], r_[5]), __fadd_rn(r_[6], r_[7]))); \
    } while (0)

__device__ __forceinline__ unsigned bf16rn(float f) {   // RN-to-nearest-even, finite
    unsigned u = __float_as_uint(f);
    return (u + 0x7fffu + ((u >> 16) & 1u)) >> 16;
}
__device__ __forceinline__ float bf2f(unsigned h) { return __uint_as_float(h << 16); }

// Exact reference-semantics distance (contiguous / strided x)
__device__ __forceinline__ float evald(const float* __restrict__ xr,
                                       const float* __restrict__ wc,
                                       float A, float w2c) {
    float m = 0.0f;
    #pragma unroll
    for (int d = 0; d < DIM; ++d) m = __fmaf_rn(xr[d], wc[d], m);
    return __fadd_rn(__fsub_rn(A, __fmul_rn(2.0f, m)), w2c);
}
__device__ __forceinline__ float evald_g(const float* __restrict__ xcol,
                                         const float* __restrict__ wc,
                                         float A, float w2c) {
    float m = 0.0f;
    #pragma unroll
    for (int d = 0; d < DIM; ++d) m = __fmaf_rn(xcol[(size_t)d * HW], wc[d], m);
    return __fadd_rn(__fsub_rn(A, __fmul_rn(2.0f, m)), w2c);
}

// ---- prep (8 blocks x 64): A-frag table + tables + atomic-slot zeroing ----
// Granule g = T*8 + s*2 + hl: 256 dwords; lane-slot l = m + 32*kh at l*4;
// code c = 32T+m, k = 16s + 8kh + e. (validated R8-R10, absmax 0.0)
__global__ __launch_bounds__(64) void vq_prep8(const float* __restrict__ weight,
                                               unsigned* __restrict__ ws) {
    if (blockIdx.x == 0 && threadIdx.x == 0) {
        *(double*)((char*)ws + WS_LSL_BYTE) = 0.0;            // loss accumulator
        *(unsigned*)((char*)ws + WS_LSL_BYTE + 8) = 0u;       // arrival counter
    }
    const int c = blockIdx.x * 64 + threadIdx.x;    // 512 codes
    const int T = c >> 5, m = c & 31;
    const float* wr = weight + c * DIM;
    float wv[DIM];
    #pragma unroll
    for (int d = 0; d < DIM; d += 4) {
        float4 t4 = *(const float4*)&wr[d];
        wv[d] = t4.x; wv[d + 1] = t4.y; wv[d + 2] = t4.z; wv[d + 3] = t4.w;
    }
    float s; NP_SUMSQ64(wv, s);
    ((float*)(ws + WS_W2_OFF))[c]  = s;             // exact pairwise ||w||^2
    ((float*)(ws + WS_W2H_OFF))[c] = 0.5f * s;      // exact (0.5*fp32)
    float sa = 0.0f;
    #pragma unroll
    for (int d = 0; d < DIM; ++d) sa = __fadd_rn(sa, fabsf(wv[d]));
    float sv = sa * 1.0002f + 1e-7f;                // sum|w| + slack

    #pragma unroll
    for (int s4 = 0; s4 < 4; ++s4) {
        const int gH = T * 8 + s4 * 2, gL = gH + 1;
        #pragma unroll
        for (int kh = 0; kh < 2; ++kh) {            // lane-half: k = 16s4+8kh+e
            unsigned hu[4], lu[4];
            #pragma unroll
            for (int p = 0; p < 4; ++p) {
                float e0 = wv[16 * s4 + 8 * kh + 2 * p];
                float e1 = wv[16 * s4 + 8 * kh + 2 * p + 1];
                unsigned h0 = bf16rn(e0), h1 = bf16rn(e1);
                float r0 = __fsub_rn(e0, bf2f(h0));   // exact residual
                float r1 = __fsub_rn(e1, bf2f(h1));
                hu[p] = h0 | (h1 << 16);
                lu[p] = bf16rn(r0) | (bf16rn(r1) << 16);
            }
            const int slot = (m + 32 * kh) * 4;
            *(uint4*)&ws[gH * 256 + slot] = make_uint4(hu[0], hu[1], hu[2], hu[3]);
            *(uint4*)&ws[gL * 256 + slot] = make_uint4(lu[0], lu[1], lu[2], lu[3]);
        }
    }
    #pragma unroll
    for (int mk = 1; mk <= 32; mk <<= 1) sv = fmaxf(sv, __shfl_xor(sv, mk));
    if (threadIdx.x == 0) ((float*)(ws + WS_SWMAX_OFF))[blockIdx.x] = sv;
}

// ---- main: R8 structure + LDS w2h/w2a + last-block ordered-atomic loss ----
// NO device-scope fences (R4 lesson). Ordering between the two atomics is by
// wave-level s_waitcnt vmcnt(0) (waits this wave's ops only, no cache flush).
__global__ __launch_bounds__(256, 3) void vq_mfma11(const float* __restrict__ x_in,
                                                    const float* __restrict__ weight,
                                                    const unsigned* __restrict__ frg,
                                                    double* __restrict__ lossacc,
                                                    float* __restrict__ out) {
    __shared__ __align__(16) unsigned dbuf[2][4096];   // 32 KB frag double-buffer
    __shared__ __align__(16) float w2h_l[NUM_K];       // 0.5*||w||^2 (acc init)
    __shared__ __align__(16) float w2a_l[NUM_K];       // exact ||w||^2 (rescue)
    __shared__ int   cntL[TILE_R];
    __shared__ unsigned short listL[TILE_R * CAP];
    __shared__ int   ilds[TILE_R];
    __shared__ float wsum[4];
    // ~39.9 KB -> 4 blocks/CU

    const int tid   = threadIdx.x;
    const int lane  = tid & 63;
    const int wid   = tid >> 6;        // 4 waves; wave owns rows [wbase, wbase+32)
    const int wbase = wid * 32;
    const int n31   = lane & 31;       // this lane's row (B col) within wave
    const int kh    = lane >> 5;       // lane half: k sub-range / code group +4kh

    const int rowbase = blockIdx.x * TILE_R;
    const int b       = rowbase >> 12;
    const int hw0     = rowbase & 4095;
    const float* xb   = x_in + (size_t)b * CHW + hw0;

    // ---- issue stage of chunk 0 (granules 0..15) ----
    #pragma unroll
    for (int i = 0; i < 4; ++i) {
        int sg = wid * 4 + i;
        GLD16(frg + sg * 256 + lane * 4, &dbuf[0][sg * 256]);
    }
    // ---- stage w2h/w2a tables into LDS (1 GLD16 per wave; validated R10) ----
    if (wid == 0)      GLD16(frg + WS_W2H_OFF       + lane * 4, (unsigned*)&w2h_l[0]);
    else if (wid == 1) GLD16(frg + WS_W2H_OFF + 256 + lane * 4, (unsigned*)&w2h_l[256]);
    else if (wid == 2) GLD16(frg + WS_W2_OFF        + lane * 4, (unsigned*)&w2a_l[0]);
    else               GLD16(frg + WS_W2_OFF  + 256 + lane * 4, (unsigned*)&w2a_l[256]);

    // ---- B fragments: NEGATED x row, hi + exact-residual lo; row-max ----
    bf16x8 bh[4], bl[4];
    float mx = 0.0f;
    const float* xp = xb + wbase + n31;
    #pragma unroll
    for (int s = 0; s < 4; ++s) {
        union { unsigned u[4]; bf16x8 v; } ch, cl;
        #pragma unroll
        for (int p = 0; p < 4; ++p) {
            const int k0 = 16 * s + 8 * kh + 2 * p;
            float x0 = xp[(size_t)k0 * HW];
            float x1 = xp[(size_t)(k0 + 1) * HW];
            mx = fmaxf(mx, fmaxf(fabsf(x0), fabsf(x1)));
            float e0 = -x0, e1 = -x1;              // negate: acc = w2h - x.w
            unsigned h0 = bf16rn(e0), h1 = bf16rn(e1);
            float r0 = __fsub_rn(e0, bf2f(h0));    // exact residual
            float r1 = __fsub_rn(e1, bf2f(h1));
            ch.u[p] = h0 | (h1 << 16);
            cl.u[p] = bf16rn(r0) | (bf16rn(r1) << 16);
        }
        bh[s] = ch.v;
        bl[s] = cl.v;
    }
    mx = fmaxf(mx, __shfl_xor(mx, 32));            // full row max (pair lanes)
    if (tid < TILE_R) cntL[tid] = 0;

    const float* swp = (const float*)(frg + WS_SWMAX_OFF);
    float SWMAX = swp[0];
    #pragma unroll
    for (int i = 1; i < 8; ++i) SWMAX = fmaxf(SWMAX, swp[i]);
    const float gthr = __fmaf_rn(WK1S * mx, 2.0f * SWMAX, WK2S);
    float thr = 3.4e38f;
    __syncthreads();   // drains stage-0 + w2h/w2a vmcnt; cntL visible

    // ---- K-loop: 8 chunks x 2 tiles (64 codes); stage next while computing ----
    for (int c = 0; c < 8; ++c) {
        const int par = c & 1;
        if (c < 7) {
            const int nxt = par ^ 1;
            #pragma unroll
            for (int i = 0; i < 4; ++i) {
                int sg = wid * 4 + i;
                GLD16(frg + (c + 1) * 4096 + sg * 256 + lane * 4,
                      &dbuf[nxt][sg * 256]);
            }
        }

        // acc init = 0.5*||w||^2 from LDS broadcast (off HBM/L2 path)
        // reg r -> code (r&3)+8*(r>>2)+4*kh : float4 groups at +0,8,16,24
        f32x16 acc0, acc1;
        {
            const float* wa = &w2h_l[(2 * c) * 32 + 4 * kh];
            float4 a0 = *(const float4*)&wa[0];
            float4 a1 = *(const float4*)&wa[8];
            float4 a2 = *(const float4*)&wa[16];
            float4 a3 = *(const float4*)&wa[24];
            acc0[0]=a0.x; acc0[1]=a0.y; acc0[2]=a0.z; acc0[3]=a0.w;
            acc0[4]=a1.x; acc0[5]=a1.y; acc0[6]=a1.z; acc0[7]=a1.w;
            acc0[8]=a2.x; acc0[9]=a2.y; acc0[10]=a2.z; acc0[11]=a2.w;
            acc0[12]=a3.x; acc0[13]=a3.y; acc0[14]=a3.z; acc0[15]=a3.w;
            const float* wb = &w2h_l[(2 * c + 1) * 32 + 4 * kh];
            float4 c0 = *(const float4*)&wb[0];
            float4 c1 = *(const float4*)&wb[8];
            float4 c2 = *(const float4*)&wb[16];
            float4 c3 = *(const float4*)&wb[24];
            acc1[0]=c0.x; acc1[1]=c0.y; acc1[2]=c0.z; acc1[3]=c0.w;
            acc1[4]=c1.x; acc1[5]=c1.y; acc1[6]=c1.z; acc1[7]=c1.w;
            acc1[8]=c2.x; acc1[9]=c2.y; acc1[10]=c2.z; acc1[11]=c2.w;
            acc1[12]=c3.x; acc1[13]=c3.y; acc1[14]=c3.z; acc1[15]=c3.w;
        }

        #pragma unroll
        for (int s = 0; s < 4; ++s) {
            bf16x8 ah0 = *(const bf16x8*)&dbuf[par][(s * 2 + 0) * 256 + lane * 4];
            bf16x8 al0 = *(const bf16x8*)&dbuf[par][(s * 2 + 1) * 256 + lane * 4];
            bf16x8 ah1 = *(const bf16x8*)&dbuf[par][(8 + s * 2 + 0) * 256 + lane * 4];
            bf16x8 al1 = *(const bf16x8*)&dbuf[par][(8 + s * 2 + 1) * 256 + lane * 4];
            acc0 = __builtin_amdgcn_mfma_f32_32x32x16_bf16(ah0, bh[s], acc0, 0, 0, 0);
            acc1 = __builtin_amdgcn_mfma_f32_32x32x16_bf16(ah1, bh[s], acc1, 0, 0, 0);
            acc0 = __builtin_amdgcn_mfma_f32_32x32x16_bf16(al0, bh[s], acc0, 0, 0, 0);
            acc1 = __builtin_amdgcn_mfma_f32_32x32x16_bf16(al1, bh[s], acc1, 0, 0, 0);
            acc0 = __builtin_amdgcn_mfma_f32_32x32x16_bf16(ah0, bl[s], acc0, 0, 0, 0);
            acc1 = __builtin_amdgcn_mfma_f32_32x32x16_bf16(ah1, bl[s], acc1, 0, 0, 0);
        }

        // ---- per-tile: in-lane min16 + ONE pair-shfl; window; collect ----
        #pragma unroll
        for (int tl = 0; tl < 2; ++tl) {
            float tmin = 3.4e38f;
            #pragma unroll
            for (int r = 0; r < 16; ++r)
                tmin = fminf(tmin, (tl ? acc1[r] : acc0[r]));
            float tlr = fminf(tmin, __shfl_xor(tmin, 32));
            thr = fminf(thr, __fadd_rn(tlr, gthr));
            if (tmin <= thr) {
                const int cb = (2 * c + tl) * 32 + 4 * kh;
                const int rr = wbase + n31;
                #pragma unroll
                for (int r = 0; r < 16; ++r) {
                    float tv = (tl ? acc1[r] : acc0[r]);
                    if (tv <= thr) {
                        int code = cb + (r & 3) + 8 * (r >> 2);
                        int cn = atomicAdd(&cntL[rr], 1);
                        if (cn < CAP) listL[rr * CAP + cn] = (unsigned short)code;
                    }
                }
            }
        }

        __syncthreads();   // dbuf[nxt] staged + all reads of dbuf[par] done
    }

    // ---- rescue: cnt==1 -> decided; else exact fp32 chain, smallest-idx ties ----
    if (lane < 32) {
        const int r   = wbase + lane;
        const int cnt = cntL[r];
        if (cnt == 1) {
            int bi = listL[r * CAP];
            ilds[r] = bi;
            out[IDX_OFF + rowbase + r] = (float)bi;
        } else if (cnt >= 2 && cnt <= CAP) {
            const float* xcol = xb + r;
            float A; NP_SUMSQ64_G(xcol, A);
            float bd = 3.4e38f; int bi = 1 << 30;
            for (int t2 = 0; t2 < cnt; ++t2) {
                int cd = listL[r * CAP + t2];
                float d2 = evald_g(xcol, weight + cd * DIM, A, w2a_l[cd]);
                if (d2 < bd || (d2 == bd && cd < bi)) { bd = d2; bi = cd; }
            }
            ilds[r] = bi;
            out[IDX_OFF + rowbase + r] = (float)bi;
        }
    }
    // cooperative exact full scan for overflow rows (rare; correctness backstop)
    for (int rr = 0; rr < 32; ++rr) {
        int r   = wbase + rr;
        int cnt = cntL[r];
        if (cnt < 1 || cnt > CAP) {
            const float* xcol = xb + r;
            float A; NP_SUMSQ64_G(xcol, A);
            float bd = 3.4e38f; int bi = 1 << 30;
            #pragma unroll
            for (int t2 = 0; t2 < 8; ++t2) {
                int cd = t2 * 64 + lane;
                float d2 = evald_g(xcol, weight + cd * DIM, A, w2a_l[cd]);
                if (d2 < bd || (d2 == bd && cd < bi)) { bd = d2; bi = cd; }
            }
            ull key = ((ull)__float_as_uint(bd) << 32) | (unsigned)bi;
            #pragma unroll
            for (int mk = 1; mk <= 32; mk <<= 1) {
                ull o = __shfl_xor(key, mk);
                if (o < key) key = o;
            }
            if (lane == 0) {
                int bi2 = (int)(key & 0xffffffffu);
                ilds[r] = bi2;
                out[IDX_OFF + rowbase + r] = (float)bi2;
            }
        }
    }
    __syncthreads();   // ilds visible

    // ---- quantize epilogue + loss (R6/R8-validated strided form) ----
    const int row = wbase + (lane & 31);
    const int dh  = (lane >> 5) << 5;           // 0 or 32
    const float* xcol = xb + row;
    const float* wr2  = weight + ilds[row] * DIM + dh;
    float* ob = out + Q_OFF + (size_t)b * CHW + hw0 + row;
    float lsum = 0.0f;
    #pragma unroll
    for (int j = 0; j < 32; ++j) {
        float xd   = xcol[(size_t)(dh + j) * HW];
        float wq   = wr2[j];
        float diff = __fsub_rn(wq, xd);
        ob[(size_t)(dh + j) * HW] = __fadd_rn(xd, diff);
        lsum = fmaf(diff, diff, lsum);
    }
    #pragma unroll
    for (int off = 32; off > 0; off >>= 1) lsum += __shfl_down(lsum, off);
    if (lane == 0) wsum[wid] = lsum;
    __syncthreads();

    // ---- last-block loss: ordered atomics, no fences ----
    if (tid == 0) {
        double s = 0.0;
        #pragma unroll
        for (int i = 0; i < 4; ++i) s += (double)wsum[i];
        unsigned* acnt = (unsigned*)(lossacc + 1);
        atomicAdd(lossacc, s);
        // wave-level wait: loss atomic globally performed before counter bump
        asm volatile("s_waitcnt vmcnt(0)" ::: "memory");
        unsigned prev = atomicAdd(acnt, 1u);
        if (prev == (unsigned)(NBLK - 1)) {
            double tot = atomicAdd(lossacc, 0.0);   // coherent read of final sum
            double m = tot / 8388608.0;
            out[LOSS_OFF] = (float)(m + 0.25 * m);  // q_latent + 0.25 * e_latent
        }
    }
}

// ---------------- scalar fallback (validated), used only if ws tiny ----------
__global__ void vq_zero(double* __restrict__ loss_acc) {
    if (threadIdx.x == 0) *loss_acc = 0.0;
}

__global__ __launch_bounds__(256) void vq_fused(const float* __restrict__ x_in,
                                                const float* __restrict__ weight,
                                                double* __restrict__ loss_acc,
                                                float* __restrict__ out) {
    __shared__ float w2s[NUM_K];
    for (int k = threadIdx.x; k < NUM_K; k += 256) {
        const float* wk = weight + k * DIM;
        float s; NP_SUMSQ64(wk, s);
        w2s[k] = s;
    }
    __syncthreads();

    const int n  = blockIdx.x * 256 + threadIdx.x;
    const int b  = n >> 12;
    const int hw = n & 4095;
    const float* xp = x_in + b * CHW + hw;
    float x[DIM];
    #pragma unroll
    for (int d = 0; d < DIM; ++d) x[d] = xp[d * HW];

    float A; NP_SUMSQ64(x, A);

    float best = 3.4e38f;
    int   bi   = 0;
    for (int k = 0; k < NUM_K; k += 4) {
        const float* w0 = weight + k * DIM;
        float m0 = 0.f, m1 = 0.f, m2 = 0.f, m3 = 0.f;
        #pragma unroll
        for (int d = 0; d < DIM; ++d) {
            float xd = x[d];
            m0 = __fmaf_rn(xd, w0[d],           m0);
            m1 = __fmaf_rn(xd, w0[DIM + d],     m1);
            m2 = __fmaf_rn(xd, w0[2 * DIM + d], m2);
            m3 = __fmaf_rn(xd, w0[3 * DIM + d], m3);
        }
        float d0 = __fadd_rn(__fsub_rn(A, __fmul_rn(2.0f, m0)), w2s[k]);
        float d1 = __fadd_rn(__fsub_rn(A, __fmul_rn(2.0f, m1)), w2s[k + 1]);
        float d2 = __fadd_rn(__fsub_rn(A, __fmul_rn(2.0f, m2)), w2s[k + 2]);
        float d3 = __fadd_rn(__fsub_rn(A, __fmul_rn(2.0f, m3)), w2s[k + 3]);
        if (d0 < best) { best = d0; bi = k; }
        if (d1 < best) { best = d1; bi = k + 1; }
        if (d2 < best) { best = d2; bi = k + 2; }
        if (d3 < best) { best = d3; bi = k + 3; }
    }
    const int idx = bi;

    out[IDX_OFF + n] = (float)idx;
    const float* qrow = weight + idx * DIM;
    float* oq = out + Q_OFF + b * CHW + hw;
    float lsum = 0.0f;
    #pragma unroll
    for (int d = 0; d < DIM; ++d) {
        float xd   = xp[d * HW];
        float diff = __fsub_rn(qrow[d], xd);
        oq[d * HW] = __fadd_rn(xd, diff);
        lsum = fmaf(diff, diff, lsum);
    }
    #pragma unroll
    for (int off = 32; off > 0; off >>= 1) lsum += __shfl_down(lsum, off);
    __shared__ float wsum[4];
    if ((threadIdx.x & 63) == 0) wsum[threadIdx.x >> 6] = lsum;
    __syncthreads();
    if (threadIdx.x == 0)
        atomicAdd(loss_acc, (double)((wsum[0] + wsum[1]) + (wsum[2] + wsum[3])));
}

__global__ void vq_finalize(const double* __restrict__ loss_acc,
                            float* __restrict__ out) {
    double m = *loss_acc / 8388608.0;
    out[LOSS_OFF] = (float)(m + 0.25 * m);
}

extern "C" void kernel_launch(void* const* d_in, const int* in_sizes, int n_in,
                              void* d_out, int out_size, void* d_ws, size_t ws_size,
                              hipStream_t stream) {
    const float* x = (const float*)d_in[0];    // inputs  [32,64,64,64] NCHW fp32
    const float* w = (const float*)d_in[1];    // weight  [512,64] fp32
    float* out = (float*)d_out;

    if (ws_size >= WS_NEED) {
        unsigned* ws32 = (unsigned*)d_ws;
        double* lossacc = (double*)((char*)d_ws + WS_LSL_BYTE);
        vq_prep8<<<8, 64, 0, stream>>>(w, ws32);
        vq_mfma11<<<NBLK, 256, 0, stream>>>(x, w, ws32, lossacc, out);
    } else {
        double* loss_acc = (double*)d_ws;
        vq_zero<<<1, 64, 0, stream>>>(loss_acc);
        vq_fused<<<512, 256, 0, stream>>>(x, w, loss_acc, out);
        vq_finalize<<<1, 1, 0, stream>>>(loss_acc, out);
    }
}

// Round 12
// 155.856 us; speedup vs baseline: 1.1492x; 1.0713x over previous
//
#include <hip/hip_runtime.h>

typedef unsigned long long ull;

#define NUM_K   512
#define DIM     64
#define N_ROWS  (32 * 64 * 64)     // 131072 rows
#define HW      4096               // 64*64
#define CHW     (64 * 4096)        // per-batch stride (C*H*W) = 2^18

// Output buffer float32, flat layout = reference return order:
//   [ discrete (131072) | quantized NCHW (8388608) | loss (1) ]
#define IDX_OFF  0
#define Q_OFF    N_ROWS
#define LOSS_OFF (N_ROWS + 32 * 64 * 4096)   // 8519680

#define CAP     8      // candidate list capacity per row
#define TILE_R  128    // rows per block (1024 blocks)
#define NBLK    (N_ROWS / TILE_R)

// Split-bf16 window (validated R2-R11): |t_hat - t_exact| <~ 6.5e-5*maxx*sumw
// one-sided; two-sided via 2*SWMAX. WK1S=1e-4 gives 1.5x margin; WK2S covers
// reorder rounding 5x.
#define WK1S    1.0e-4f
#define WK2S    2.0e-5f

// Workspace (dwords):
//   [0,32768)  A-frag table: 128 granules x 256 dwords
//   [32768,33280) w2all (exact ||w||^2)   [33280,33792) w2h (0.5*||w||^2)
//   [33792,33800) 8 swmax partials
//   bytes [147456,147456+512): 8 loss slots (double, 64B apart)
//   bytes [147968,147972): arrival counter
#define WS_W2_OFF    32768
#define WS_W2H_OFF   33280
#define WS_SWMAX_OFF 33792
#define WS_LSL_BYTE  147456
#define WS_CNT_BYTE  147968
#define WS_NEED      (147968 + 16)

typedef __attribute__((ext_vector_type(8)))  short bf16x8;   // 8 bf16 = 4 VGPRs
typedef __attribute__((ext_vector_type(16))) float f32x16;   // 32x32 acc

typedef unsigned uGLB __attribute__((address_space(1)));
typedef unsigned uLDS __attribute__((address_space(3)));
// async global->LDS, 16B/lane; LDS dest is wave-uniform base + lane*16
#define GLD16(g, l) __builtin_amdgcn_global_load_lds((const uGLB*)(g), (uLDS*)(l), 16, 0, 0)

// numpy pairwise_sum (n=64) of squares, contiguous (validated bit-exact)
#define NP_SUMSQ64(SRC, DST)                                                   \
    do {                                                                       \
        float r_[8];                                                           \
        _Pragma("unroll")                                                      \
        for (int j_ = 0; j_ < 8; ++j_) r_[j_] = __fmul_rn((SRC)[j_], (SRC)[j_]); \
        _Pragma("unroll")                                                      \
        for (int i_ = 8; i_ < 64; i_ += 8) {                                   \
            _Pragma("unroll")                                                  \
            for (int j_ = 0; j_ < 8; ++j_)                                     \
                r_[j_] = __fadd_rn(r_[j_], __fmul_rn((SRC)[i_ + j_], (SRC)[i_ + j_])); \
        }                                                                      \
        (DST) = __fadd_rn(__fadd_rn(__fadd_rn(r_[0], r_[1]), __fadd_rn(r_[2], r_[3])), \
                          __fadd_rn(__fadd_rn(r_[4], r_[5]), __fadd_rn(r_[6], r_[7]))); \
    } while (0)

// same pairwise order, strided source (element d at (XC)[d*HW])
#define NP_SUMSQ64_G(XC, DST)                                                  \
    do {                                                                       \
        float r_[8];                                                           \
        _Pragma("unroll")                                                      \
        for (int j_ = 0; j_ < 8; ++j_) {                                       \
            float v_ = (XC)[(size_t)j_ * HW];                                  \
            r_[j_] = __fmul_rn(v_, v_);                                        \
        }                                                                      \
        _Pragma("unroll")                                                      \
        for (int i_ = 8; i_ < 64; i_ += 8) {                                   \
            _Pragma("unroll")                                                  \
            for (int j_ = 0; j_ < 8; ++j_) {                                   \
                float v_ = (XC)[(size_t)(i_ + j_) * HW];                       \
                r_[j_] = __fadd_rn(r_[j_], __fmul_rn(v_, v_));                 \
            }                                                                  \
        }                                                                      \
        (DST) = __fadd_rn(__fadd_rn(__fadd_rn(r_[0], r_[1]), __fadd_rn(r_[2], r_[3])), \
                          __fadd_rn(__fadd_rn(r_[4], r_[5]), __fadd_rn(r_[6], r_[7]))); \
    } while (0)

__device__ __forceinline__ unsigned bf16rn(float f) {   // RN-to-nearest-even, finite
    unsigned u = __float_as_uint(f);
    return (u + 0x7fffu + ((u >> 16) & 1u)) >> 16;
}
__device__ __forceinline__ float bf2f(unsigned h) { return __uint_as_float(h << 16); }

// Exact reference-semantics distance (contiguous / strided x)
__device__ __forceinline__ float evald(const float* __restrict__ xr,
                                       const float* __restrict__ wc,
                                       float A, float w2c) {
    float m = 0.0f;
    #pragma unroll
    for (int d = 0; d < DIM; ++d) m = __fmaf_rn(xr[d], wc[d], m);
    return __fadd_rn(__fsub_rn(A, __fmul_rn(2.0f, m)), w2c);
}
__device__ __forceinline__ float evald_g(const float* __restrict__ xcol,
                                         const float* __restrict__ wc,
                                         float A, float w2c) {
    float m = 0.0f;
    #pragma unroll
    for (int d = 0; d < DIM; ++d) m = __fmaf_rn(xcol[(size_t)d * HW], wc[d], m);
    return __fadd_rn(__fsub_rn(A, __fmul_rn(2.0f, m)), w2c);
}

// ---- prep (8 blocks x 64): A-frag table + tables + atomic-slot zeroing ----
// Granule g = T*8 + s*2 + hl: 256 dwords; lane-slot l = m + 32*kh at l*4;
// code c = 32T+m, k = 16s + 8kh + e. (validated R8-R11, absmax 0.0)
__global__ __launch_bounds__(64) void vq_prep8(const float* __restrict__ weight,
                                               unsigned* __restrict__ ws) {
    if (blockIdx.x == 0 && threadIdx.x < 8)
        *(double*)((char*)ws + WS_LSL_BYTE + threadIdx.x * 64) = 0.0;  // loss slots
    if (blockIdx.x == 0 && threadIdx.x == 8)
        *(unsigned*)((char*)ws + WS_CNT_BYTE) = 0u;                    // arrival cnt
    const int c = blockIdx.x * 64 + threadIdx.x;    // 512 codes
    const int T = c >> 5, m = c & 31;
    const float* wr = weight + c * DIM;
    float wv[DIM];
    #pragma unroll
    for (int d = 0; d < DIM; d += 4) {
        float4 t4 = *(const float4*)&wr[d];
        wv[d] = t4.x; wv[d + 1] = t4.y; wv[d + 2] = t4.z; wv[d + 3] = t4.w;
    }
    float s; NP_SUMSQ64(wv, s);
    ((float*)(ws + WS_W2_OFF))[c]  = s;             // exact pairwise ||w||^2
    ((float*)(ws + WS_W2H_OFF))[c] = 0.5f * s;      // exact (0.5*fp32)
    float sa = 0.0f;
    #pragma unroll
    for (int d = 0; d < DIM; ++d) sa = __fadd_rn(sa, fabsf(wv[d]));
    float sv = sa * 1.0002f + 1e-7f;                // sum|w| + slack

    #pragma unroll
    for (int s4 = 0; s4 < 4; ++s4) {
        const int gH = T * 8 + s4 * 2, gL = gH + 1;
        #pragma unroll
        for (int kh = 0; kh < 2; ++kh) {            // lane-half: k = 16s4+8kh+e
            unsigned hu[4], lu[4];
            #pragma unroll
            for (int p = 0; p < 4; ++p) {
                float e0 = wv[16 * s4 + 8 * kh + 2 * p];
                float e1 = wv[16 * s4 + 8 * kh + 2 * p + 1];
                unsigned h0 = bf16rn(e0), h1 = bf16rn(e1);
                float r0 = __fsub_rn(e0, bf2f(h0));   // exact residual
                float r1 = __fsub_rn(e1, bf2f(h1));
                hu[p] = h0 | (h1 << 16);
                lu[p] = bf16rn(r0) | (bf16rn(r1) << 16);
            }
            const int slot = (m + 32 * kh) * 4;
            *(uint4*)&ws[gH * 256 + slot] = make_uint4(hu[0], hu[1], hu[2], hu[3]);
            *(uint4*)&ws[gL * 256 + slot] = make_uint4(lu[0], lu[1], lu[2], lu[3]);
        }
    }
    #pragma unroll
    for (int mk = 1; mk <= 32; mk <<= 1) sv = fmaxf(sv, __shfl_xor(sv, mk));
    if (threadIdx.x == 0) ((float*)(ws + WS_SWMAX_OFF))[blockIdx.x] = sv;
}

// ---- main: EXACT R8 loop (global w2h acc-init, global w2g rescue) ----
// + last-block striped-atomic loss (8 slots, validated protocol from R11).
__global__ __launch_bounds__(256, 3) void vq_mfma12(const float* __restrict__ x_in,
                                                    const float* __restrict__ weight,
                                                    const unsigned* __restrict__ frg,
                                                    const float* __restrict__ w2g,
                                                    const float* __restrict__ w2h,
                                                    char* __restrict__ lossraw,
                                                    float* __restrict__ out) {
    __shared__ __align__(16) unsigned dbuf[2][4096];   // 32 KB frag double-buffer
    __shared__ int   cntL[TILE_R];
    __shared__ unsigned short listL[TILE_R * CAP];
    __shared__ int   ilds[TILE_R];
    __shared__ float wsum[4];
    // ~35.4 KB (R8 envelope)

    const int tid   = threadIdx.x;
    const int lane  = tid & 63;
    const int wid   = tid >> 6;        // 4 waves; wave owns rows [wbase, wbase+32)
    const int wbase = wid * 32;
    const int n31   = lane & 31;       // this lane's row (B col) within wave
    const int kh    = lane >> 5;       // lane half: k sub-range / code group +4kh

    const int rowbase = blockIdx.x * TILE_R;
    const int b       = rowbase >> 12;
    const int hw0     = rowbase & 4095;
    const float* xb   = x_in + (size_t)b * CHW + hw0;

    // ---- issue stage of chunk 0 (granules 0..15) ----
    #pragma unroll
    for (int i = 0; i < 4; ++i) {
        int sg = wid * 4 + i;
        GLD16(frg + sg * 256 + lane * 4, &dbuf[0][sg * 256]);
    }

    // ---- B fragments: NEGATED x row, hi + exact-residual lo; row-max ----
    bf16x8 bh[4], bl[4];
    float mx = 0.0f;
    const float* xp = xb + wbase + n31;
    #pragma unroll
    for (int s = 0; s < 4; ++s) {
        union { unsigned u[4]; bf16x8 v; } ch, cl;
        #pragma unroll
        for (int p = 0; p < 4; ++p) {
            const int k0 = 16 * s + 8 * kh + 2 * p;
            float x0 = xp[(size_t)k0 * HW];
            float x1 = xp[(size_t)(k0 + 1) * HW];
            mx = fmaxf(mx, fmaxf(fabsf(x0), fabsf(x1)));
            float e0 = -x0, e1 = -x1;              // negate: acc = w2h - x.w
            unsigned h0 = bf16rn(e0), h1 = bf16rn(e1);
            float r0 = __fsub_rn(e0, bf2f(h0));    // exact residual
            float r1 = __fsub_rn(e1, bf2f(h1));
            ch.u[p] = h0 | (h1 << 16);
            cl.u[p] = bf16rn(r0) | (bf16rn(r1) << 16);
        }
        bh[s] = ch.v;
        bl[s] = cl.v;
    }
    mx = fmaxf(mx, __shfl_xor(mx, 32));            // full row max (pair lanes)
    if (tid < TILE_R) cntL[tid] = 0;

    const float* swp = (const float*)(frg + WS_SWMAX_OFF);
    float SWMAX = swp[0];
    #pragma unroll
    for (int i = 1; i < 8; ++i) SWMAX = fmaxf(SWMAX, swp[i]);
    const float gthr = __fmaf_rn(WK1S * mx, 2.0f * SWMAX, WK2S);
    float thr = 3.4e38f;
    __syncthreads();   // drains stage-0 vmcnt + cntL visible

    // ---- K-loop: 8 chunks x 2 tiles (64 codes); stage next while computing ----
    for (int c = 0; c < 8; ++c) {
        const int par = c & 1;
        if (c < 7) {
            const int nxt = par ^ 1;
            #pragma unroll
            for (int i = 0; i < 4; ++i) {
                int sg = wid * 4 + i;
                GLD16(frg + (c + 1) * 4096 + sg * 256 + lane * 4,
                      &dbuf[nxt][sg * 256]);
            }
        }

        // acc init = 0.5*||w||^2 from GLOBAL (R8 form: overlaps on TA/L2 pipe)
        // reg r -> code (r&3)+8*(r>>2)+4*kh : float4 groups at +0,8,16,24
        f32x16 acc0, acc1;
        {
            const float* wa = w2h + (2 * c) * 32 + 4 * kh;
            float4 a0 = *(const float4*)&wa[0];
            float4 a1 = *(const float4*)&wa[8];
            float4 a2 = *(const float4*)&wa[16];
            float4 a3 = *(const float4*)&wa[24];
            acc0[0]=a0.x; acc0[1]=a0.y; acc0[2]=a0.z; acc0[3]=a0.w;
            acc0[4]=a1.x; acc0[5]=a1.y; acc0[6]=a1.z; acc0[7]=a1.w;
            acc0[8]=a2.x; acc0[9]=a2.y; acc0[10]=a2.z; acc0[11]=a2.w;
            acc0[12]=a3.x; acc0[13]=a3.y; acc0[14]=a3.z; acc0[15]=a3.w;
            const float* wb = w2h + (2 * c + 1) * 32 + 4 * kh;
            float4 c0 = *(const float4*)&wb[0];
            float4 c1 = *(const float4*)&wb[8];
            float4 c2 = *(const float4*)&wb[16];
            float4 c3 = *(const float4*)&wb[24];
            acc1[0]=c0.x; acc1[1]=c0.y; acc1[2]=c0.z; acc1[3]=c0.w;
            acc1[4]=c1.x; acc1[5]=c1.y; acc1[6]=c1.z; acc1[7]=c1.w;
            acc1[8]=c2.x; acc1[9]=c2.y; acc1[10]=c2.z; acc1[11]=c2.w;
            acc1[12]=c3.x; acc1[13]=c3.y; acc1[14]=c3.z; acc1[15]=c3.w;
        }

        #pragma unroll
        for (int s = 0; s < 4; ++s) {
            bf16x8 ah0 = *(const bf16x8*)&dbuf[par][(s * 2 + 0) * 256 + lane * 4];
            bf16x8 al0 = *(const bf16x8*)&dbuf[par][(s * 2 + 1) * 256 + lane * 4];
            bf16x8 ah1 = *(const bf16x8*)&dbuf[par][(8 + s * 2 + 0) * 256 + lane * 4];
            bf16x8 al1 = *(const bf16x8*)&dbuf[par][(8 + s * 2 + 1) * 256 + lane * 4];
            acc0 = __builtin_amdgcn_mfma_f32_32x32x16_bf16(ah0, bh[s], acc0, 0, 0, 0);
            acc1 = __builtin_amdgcn_mfma_f32_32x32x16_bf16(ah1, bh[s], acc1, 0, 0, 0);
            acc0 = __builtin_amdgcn_mfma_f32_32x32x16_bf16(al0, bh[s], acc0, 0, 0, 0);
            acc1 = __builtin_amdgcn_mfma_f32_32x32x16_bf16(al1, bh[s], acc1, 0, 0, 0);
            acc0 = __builtin_amdgcn_mfma_f32_32x32x16_bf16(ah0, bl[s], acc0, 0, 0, 0);
            acc1 = __builtin_amdgcn_mfma_f32_32x32x16_bf16(ah1, bl[s], acc1, 0, 0, 0);
        }

        // ---- per-tile: in-lane min16 + ONE pair-shfl; window; collect ----
        #pragma unroll
        for (int tl = 0; tl < 2; ++tl) {
            float tmin = 3.4e38f;
            #pragma unroll
            for (int r = 0; r < 16; ++r)
                tmin = fminf(tmin, (tl ? acc1[r] : acc0[r]));
            float tlr = fminf(tmin, __shfl_xor(tmin, 32));
            thr = fminf(thr, __fadd_rn(tlr, gthr));
            if (tmin <= thr) {
                const int cb = (2 * c + tl) * 32 + 4 * kh;
                const int rr = wbase + n31;
                #pragma unroll
                for (int r = 0; r < 16; ++r) {
                    float tv = (tl ? acc1[r] : acc0[r]);
                    if (tv <= thr) {
                        int code = cb + (r & 3) + 8 * (r >> 2);
                        int cn = atomicAdd(&cntL[rr], 1);
                        if (cn < CAP) listL[rr * CAP + cn] = (unsigned short)code;
                    }
                }
            }
        }

        __syncthreads();   // dbuf[nxt] staged + all reads of dbuf[par] done
    }

    // ---- rescue: cnt==1 -> decided; else exact fp32 chain, smallest-idx ties ----
    if (lane < 32) {
        const int r   = wbase + lane;
        const int cnt = cntL[r];
        if (cnt == 1) {
            int bi = listL[r * CAP];
            ilds[r] = bi;
            out[IDX_OFF + rowbase + r] = (float)bi;
        } else if (cnt >= 2 && cnt <= CAP) {
            const float* xcol = xb + r;
            float A; NP_SUMSQ64_G(xcol, A);
            float bd = 3.4e38f; int bi = 1 << 30;
            for (int t2 = 0; t2 < cnt; ++t2) {
                int cd = listL[r * CAP + t2];
                float d2 = evald_g(xcol, weight + cd * DIM, A, w2g[cd]);
                if (d2 < bd || (d2 == bd && cd < bi)) { bd = d2; bi = cd; }
            }
            ilds[r] = bi;
            out[IDX_OFF + rowbase + r] = (float)bi;
        }
    }
    // cooperative exact full scan for overflow rows (rare; correctness backstop)
    for (int rr = 0; rr < 32; ++rr) {
        int r   = wbase + rr;
        int cnt = cntL[r];
        if (cnt < 1 || cnt > CAP) {
            const float* xcol = xb + r;
            float A; NP_SUMSQ64_G(xcol, A);
            float bd = 3.4e38f; int bi = 1 << 30;
            #pragma unroll
            for (int t2 = 0; t2 < 8; ++t2) {
                int cd = t2 * 64 + lane;
                float d2 = evald_g(xcol, weight + cd * DIM, A, w2g[cd]);
                if (d2 < bd || (d2 == bd && cd < bi)) { bd = d2; bi = cd; }
            }
            ull key = ((ull)__float_as_uint(bd) << 32) | (unsigned)bi;
            #pragma unroll
            for (int mk = 1; mk <= 32; mk <<= 1) {
                ull o = __shfl_xor(key, mk);
                if (o < key) key = o;
            }
            if (lane == 0) {
                int bi2 = (int)(key & 0xffffffffu);
                ilds[r] = bi2;
                out[IDX_OFF + rowbase + r] = (float)bi2;
            }
        }
    }
    __syncthreads();   // ilds visible

    // ---- quantize epilogue + loss (R6/R8-validated strided form) ----
    const int row = wbase + (lane & 31);
    const int dh  = (lane >> 5) << 5;           // 0 or 32
    const float* xcol = xb + row;
    const float* wr2  = weight + ilds[row] * DIM + dh;
    float* ob = out + Q_OFF + (size_t)b * CHW + hw0 + row;
    float lsum = 0.0f;
    #pragma unroll
    for (int j = 0; j < 32; ++j) {
        float xd   = xcol[(size_t)(dh + j) * HW];
        float wq   = wr2[j];
        float diff = __fsub_rn(wq, xd);
        ob[(size_t)(dh + j) * HW] = __fadd_rn(xd, diff);
        lsum = fmaf(diff, diff, lsum);
    }
    #pragma unroll
    for (int off = 32; off > 0; off >>= 1) lsum += __shfl_down(lsum, off);
    if (lane == 0) wsum[wid] = lsum;
    __syncthreads();

    // ---- last-block loss: striped atomics (8 slots, 64B apart), no fences ----
    if (tid == 0) {
        double s = 0.0;
        #pragma unroll
        for (int i = 0; i < 4; ++i) s += (double)wsum[i];
        double* slot = (double*)(lossraw + (blockIdx.x & 7) * 64);
        unsigned* acnt = (unsigned*)(lossraw + (WS_CNT_BYTE - WS_LSL_BYTE));
        atomicAdd(slot, s);
        // wave-level wait: slot atomic globally performed before counter bump
        asm volatile("s_waitcnt vmcnt(0)" ::: "memory");
        unsigned prev = atomicAdd(acnt, 1u);
        if (prev == (unsigned)(NBLK - 1)) {
            double tot = 0.0;
            #pragma unroll
            for (int i = 0; i < 8; ++i)
                tot += atomicAdd((double*)(lossraw + i * 64), 0.0);  // coherent reads
            double m = tot / 8388608.0;
            out[LOSS_OFF] = (float)(m + 0.25 * m);  // q_latent + 0.25 * e_latent
        }
    }
}

// ---------------- scalar fallback (validated), used only if ws tiny ----------
__global__ void vq_zero(double* __restrict__ loss_acc) {
    if (threadIdx.x == 0) *loss_acc = 0.0;
}

__global__ __launch_bounds__(256) void vq_fused(const float* __restrict__ x_in,
                                                const float* __restrict__ weight,
                                                double* __restrict__ loss_acc,
                                                float* __restrict__ out) {
    __shared__ float w2s[NUM_K];
    for (int k = threadIdx.x; k < NUM_K; k += 256) {
        const float* wk = weight + k * DIM;
        float s; NP_SUMSQ64(wk, s);
        w2s[k] = s;
    }
    __syncthreads();

    const int n  = blockIdx.x * 256 + threadIdx.x;
    const int b  = n >> 12;
    const int hw = n & 4095;
    const float* xp = x_in + b * CHW + hw;
    float x[DIM];
    #pragma unroll
    for (int d = 0; d < DIM; ++d) x[d] = xp[d * HW];

    float A; NP_SUMSQ64(x, A);

    float best = 3.4e38f;
    int   bi   = 0;
    for (int k = 0; k < NUM_K; k += 4) {
        const float* w0 = weight + k * DIM;
        float m0 = 0.f, m1 = 0.f, m2 = 0.f, m3 = 0.f;
        #pragma unroll
        for (int d = 0; d < DIM; ++d) {
            float xd = x[d];
            m0 = __fmaf_rn(xd, w0[d],           m0);
            m1 = __fmaf_rn(xd, w0[DIM + d],     m1);
            m2 = __fmaf_rn(xd, w0[2 * DIM + d], m2);
            m3 = __fmaf_rn(xd, w0[3 * DIM + d], m3);
        }
        float d0 = __fadd_rn(__fsub_rn(A, __fmul_rn(2.0f, m0)), w2s[k]);
        float d1 = __fadd_rn(__fsub_rn(A, __fmul_rn(2.0f, m1)), w2s[k + 1]);
        float d2 = __fadd_rn(__fsub_rn(A, __fmul_rn(2.0f, m2)), w2s[k + 2]);
        float d3 = __fadd_rn(__fsub_rn(A, __fmul_rn(2.0f, m3)), w2s[k + 3]);
        if (d0 < best) { best = d0; bi = k; }
        if (d1 < best) { best = d1; bi = k + 1; }
        if (d2 < best) { best = d2; bi = k + 2; }
        if (d3 < best) { best = d3; bi = k + 3; }
    }
    const int idx = bi;

    out[IDX_OFF + n] = (float)idx;
    const float* qrow = weight + idx * DIM;
    float* oq = out + Q_OFF + b * CHW + hw;
    float lsum = 0.0f;
    #pragma unroll
    for (int d = 0; d < DIM; ++d) {
        float xd   = xp[d * HW];
        float diff = __fsub_rn(qrow[d], xd);
        oq[d * HW] = __fadd_rn(xd, diff);
        lsum = fmaf(diff, diff, lsum);
    }
    #pragma unroll
    for (int off = 32; off > 0; off >>= 1) lsum += __shfl_down(lsum, off);
    __shared__ float wsum[4];
    if ((threadIdx.x & 63) == 0) wsum[threadIdx.x >> 6] = lsum;
    __syncthreads();
    if (threadIdx.x == 0)
        atomicAdd(loss_acc, (double)((wsum[0] + wsum[1]) + (wsum[2] + wsum[3])));
}

__global__ void vq_finalize(const double* __restrict__ loss_acc,
                            float* __restrict__ out) {
    double m = *loss_acc / 8388608.0;
    out[LOSS_OFF] = (float)(m + 0.25 * m);
}

extern "C" void kernel_launch(void* const* d_in, const int* in_sizes, int n_in,
                              void* d_out, int out_size, void* d_ws, size_t ws_size,
                              hipStream_t stream) {
    const float* x = (const float*)d_in[0];    // inputs  [32,64,64,64] NCHW fp32
    const float* w = (const float*)d_in[1];    // weight  [512,64] fp32
    float* out = (float*)d_out;

    if (ws_size >= WS_NEED) {
        unsigned* ws32 = (unsigned*)d_ws;
        const float* w2g = (const float*)(ws32 + WS_W2_OFF);
        const float* w2h = (const float*)(ws32 + WS_W2H_OFF);
        char* lossraw = (char*)d_ws + WS_LSL_BYTE;
        vq_prep8<<<8, 64, 0, stream>>>(w, ws32);
        vq_mfma12<<<NBLK, 256, 0, stream>>>(x, w, ws32, w2g, w2h, lossraw, out);
    } else {
        double* loss_acc = (double*)d_ws;
        vq_zero<<<1, 64, 0, stream>>>(loss_acc);
        vq_fused<<<512, 256, 0, stream>>>(x, w, loss_acc, out);
        vq_finalize<<<1, 1, 0, stream>>>(loss_acc, out);
    }
}